// Round 3
// baseline (373.031 us; speedup 1.0000x reference)
//
#include <hip/hip_runtime.h>
#include <math.h>

// Fused dual-LeNet + len-19 full convolution + log.
// Round-13: conv1 moves to MFMA (v_mfma_f32_32x32x16_f16), shift-packed.
//  * B operand: N = 4 x-shifts x 6 channels = 24/32 cols used. B[k'][(s,ch)]
//    = w1[ch][ky][kx'-s] over an 8-wide kx' window -> one A-row (8-wide
//    image patch row) yields 4 output x-positions x 6 channels.
//  * A operand: image staged as interleaved (hi,lo) f16 pairs (x = hi+lo
//    exact; only w1 is f16-quantized). k' = ky*16 + kx'*2 + h -> K = 80 =
//    exactly 5 k-steps of 16; each A-frag is ONE aligned ds_read_b128.
//  * M = 32 rows = Y0 0..23 (+8 pad, write-masked). 12 tiles/wave
//    (2 inst x 6 x-blocks), 5 MFMA each.
//  * 2x2 pool fully in-register (y-pairs = reg pairs) + shfl_xor(8) for
//    x-pairs (adjacent shift columns); ds_write_b16 into unchanged s_p1h.
//  * replaces ~2900 VALU + 290 LDS ops/thread with ~1100 VALU + 60 b128.
// conv2 (MFMA, R11), fc1/fc2/fc3/tail (R12) unchanged. LDS 45.4 KB, 3 blk/CU.

#define SPB 4            // samples per block (2 pairs, 8 instances)
#define P1H_IN 440       // s_p1h instance stride in half2
#define P1H_IC 144       // channel-pair stride in half2 (3 pairs per inst)

typedef _Float16 f16x2 __attribute__((ext_vector_type(2)));
typedef _Float16 half8 __attribute__((ext_vector_type(8)));
typedef float floatx4 __attribute__((ext_vector_type(4)));
typedef float floatx16 __attribute__((ext_vector_type(16)));

__global__ __launch_bounds__(256, 3) void lenet_fused(
    const float* __restrict__ x,     // [B,2,28,28]
    const float* __restrict__ cw1,   // [6,1,5,5]
    const float* __restrict__ cb1,   // [6]
    const float* __restrict__ cw2,   // [16,6,5,5]
    const float* __restrict__ cb2,   // [16]
    const float* __restrict__ fw1,   // [120,256]
    const float* __restrict__ fb1,   // [120]
    const float* __restrict__ fw2,   // [84,120]
    const float* __restrict__ fb2,   // [84]
    const float* __restrict__ fw3,   // [10,84]
    const float* __restrict__ fb3,   // [10]
    float* __restrict__ out)         // [B,19]
{
    const int tid = threadIdx.x;
    const int b0  = blockIdx.x * SPB;

    __shared__ __align__(16) float s_pool[8 * 784];      // 25088 B (imgHL; reused)
    __shared__ __align__(16) f16x2 s_p1h [8 * P1H_IN];   // 14080 B
    __shared__ __align__(16) float s_w1t [25 * 8];       //   800 B  [k][o]
    __shared__ float s_b1[8];
    __shared__ __align__(16) f16x2 s_w2A [16 * 84];      //  5376 B  [o][kp]
    __shared__ float s_b2[16];
    // total ~45.4 KB -> 3 blocks/CU

    f16x2* s_imgHL = (f16x2*)s_pool;  // [8 inst][28][28] (hi,lo) pairs
    float* s_p2  = s_pool;           // 2048
    float* s_f1  = s_pool + 2048;    // 960
    float* s_f2  = s_pool + 3008;    // 672
    float* s_log = s_pool + 3680;    // 80

    // ---- stage images (hi/lo split) + weights ----
    {
        const float* xb = x + (size_t)b0 * 1568;
        for (int i = tid; i < 6272; i += 256) {
            float v = xb[i];
            _Float16 hi = (_Float16)v;
            _Float16 lo = (_Float16)(v - (float)hi);
            f16x2 p; p.x = hi; p.y = lo;
            s_imgHL[i] = p;
        }
    }
    for (int i = tid; i < 150; i += 256) {       // cw1 -> [k][o], stride 8
        int o = i / 25, k = i % 25;
        s_w1t[k * 8 + o] = cw1[i];
    }
    for (int i = tid; i < 16 * 84; i += 256) {   // cw2 -> MFMA A rows [o][kp]
        int o = i / 84, kp = i % 84;
        f16x2 w2;
        if (kp < 75) {
            int icp = kp / 25, r = kp % 25;      // kp = icp*25 + ky*5 + kx
            float we = cw2[o * 150 + (2 * icp    ) * 25 + r];
            float wo = cw2[o * 150 + (2 * icp + 1) * 25 + r];
            w2.x = (_Float16)we; w2.y = (_Float16)wo;
        } else {
            w2.x = (_Float16)0.f; w2.y = (_Float16)0.f;
        }
        s_w2A[i] = w2;
    }
    if (tid < 8)  s_b1[tid] = (tid < 6) ? cb1[tid] : 0.f;
    if (tid < 16) s_b2[tid] = cb2[tid];
    __syncthreads();

    // ---- conv1 5x5 (1->6) + pool2x2 + relu : MFMA 32x32x16 f16 ----
    // D[32 rows = Y0 (24 valid)][32 cols = (s,ch), 24 valid]; per tile
    // (inst, xb): 5 k-steps (ky), A-frag = one b128 of 4 (hi,lo) pairs.
    {
        const int lane = tid & 63;
        const int wv   = tid >> 6;
        const int l5   = lane >> 5;
        const int cn   = lane & 31;
        const int s    = cn >> 3;                // x-shift 0..3
        const int ch   = cn & 7;                 // channel 0..7 (<6 valid)
        const int Y0   = cn < 24 ? cn : 23;      // A-row pixel row (clamped)

        // B fragments: B[k' = ks*16 + l5*8 + j][(s,ch)] = w1[ch][ks][kx'-s],
        // kx' = l5*4 + (j>>1), both h-slots identical.
        half8 bfr[5];
#pragma unroll
        for (int ks = 0; ks < 5; ++ks) {
            float w4[4];
#pragma unroll
            for (int q = 0; q < 4; ++q) {
                int kx = l5 * 4 + q - s;
                float wq = 0.f;
                if (ch < 6 && kx >= 0 && kx <= 4)
                    wq = s_w1t[(ks * 5 + kx) * 8 + ch];
                w4[q] = wq;
            }
            half8 b;
            b[0] = (_Float16)w4[0]; b[1] = b[0];
            b[2] = (_Float16)w4[1]; b[3] = b[2];
            b[4] = (_Float16)w4[2]; b[5] = b[4];
            b[6] = (_Float16)w4[3]; b[7] = b[6];
            bfr[ks] = b;
        }
        const float bch = s_b1[ch];
        const int   ybase = Y0 * 28 + l5 * 4;    // half2 units (mod 4 == 0)
        const bool  wrl   = ((s & 1) == 0) && (ch < 6);
        _Float16* p1w = (_Float16*)s_p1h;

#pragma unroll
        for (int ih = 0; ih < 2; ++ih) {
            const int inst = wv + 4 * ih;
            const f16x2* ip = s_imgHL + inst * 784 + ybase;
            const int wb = (inst * P1H_IN + (ch >> 1) * P1H_IC) * 2 + (ch & 1);
#pragma unroll
            for (int xbi = 0; xbi < 6; ++xbi) {
                const f16x2* pa = ip + xbi * 4;
                floatx16 acc = {0.f,0.f,0.f,0.f, 0.f,0.f,0.f,0.f,
                                0.f,0.f,0.f,0.f, 0.f,0.f,0.f,0.f};
#pragma unroll
                for (int ks = 0; ks < 5; ++ks) {
                    half8 a = *(const half8*)(pa + ks * 28);
                    acc = __builtin_amdgcn_mfma_f32_32x32x16_f16(
                        a, bfr[ks], acc, 0, 0, 0);
                }
                // pool + bias + relu + f16 store.
                // D row = (reg&3) + 8*(reg>>2) + 4*l5 = Y0; col = (s,ch).
                const int px2 = (xbi * 2 + (s >> 1)) * 2;   // px in halves
#pragma unroll
                for (int d = 0; d < 4; ++d) {
#pragma unroll
                    for (int cp = 0; cp < 2; ++cp) {
                        float vy = fmaxf(acc[4 * d + 2 * cp],
                                         acc[4 * d + 2 * cp + 1]); // y-pool
                        float vo = __shfl_xor(vy, 8);              // s^1 col
                        float vp = fmaxf(vy, vo);                  // x-pool
                        float r  = fmaxf(vp + bch, 0.f);
                        int  py  = cp + 4 * d + 2 * l5;
                        if (wrl && py < 12)
                            p1w[wb + py * 24 + px2] = (_Float16)r;
                    }
                }
            }
        }
    }
    __syncthreads();

    // ---- conv2 5x5 (6->16) + pool2x2 + relu : MFMA 16x16x32 f16 ----
    {
        const int lane = tid & 63;
        const int wv0  = tid >> 6;               // instance pair: wv0, wv0+4
        const int g    = lane >> 4;              // k-group
        const int cn   = lane & 15;              // A row (=o) / B col (=n%16)

        half8 afr[5];
        const _Float16* wA = (const _Float16*)s_w2A;
#pragma unroll
        for (int ks = 0; ks < 5; ++ks)
            afr[ks] = *(const half8*)(wA + cn * 168 + ks * 32 + g * 8);

        float bias4[4];
#pragma unroll
        for (int r = 0; r < 4; ++r) bias4[r] = s_b2[g * 4 + r];

        const int csb = (cn >> 3) * 12 + (cn & 7);           // + 24*ntl per tile
        const f16x2* pbA = s_p1h + wv0 * P1H_IN + csb;
        const f16x2* pbB = pbA + 4 * P1H_IN;

        floatx4 zero4 = {0.f, 0.f, 0.f, 0.f};
        floatx4 accA[4] = {zero4, zero4, zero4, zero4};
        floatx4 accB[4] = {zero4, zero4, zero4, zero4};

#pragma unroll
        for (int ks = 0; ks < 5; ++ks) {
            int ko[4];
#pragma unroll
            for (int j = 0; j < 4; ++j) {
                int kp = ks * 16 + g * 4 + j;
                kp = kp > 74 ? 74 : kp;          // clamp: garbage meets zero A
                int icp = (int)((unsigned)kp / 25u);
                int r   = kp - icp * 25;
                int ky  = (int)((unsigned)r / 5u);
                int kx  = r - ky * 5;
                ko[j] = icp * P1H_IC + ky * 12 + kx;
            }
#pragma unroll
            for (int ntl = 0; ntl < 4; ++ntl) {
                union { half8 h8; f16x2 h2[4]; } bpA, bpB;
                bpA.h2[0] = pbA[ko[0] + 24 * ntl];
                bpA.h2[1] = pbA[ko[1] + 24 * ntl];
                bpA.h2[2] = pbA[ko[2] + 24 * ntl];
                bpA.h2[3] = pbA[ko[3] + 24 * ntl];
                bpB.h2[0] = pbB[ko[0] + 24 * ntl];
                bpB.h2[1] = pbB[ko[1] + 24 * ntl];
                bpB.h2[2] = pbB[ko[2] + 24 * ntl];
                bpB.h2[3] = pbB[ko[3] + 24 * ntl];
                accA[ntl] = __builtin_amdgcn_mfma_f32_16x16x32_f16(
                    afr[ks], bpA.h8, accA[ntl], 0, 0, 0);
                accB[ntl] = __builtin_amdgcn_mfma_f32_16x16x32_f16(
                    afr[ks], bpB.h8, accB[ntl], 0, 0, 0);
            }
        }

        const int px = (lane & 7) >> 1;
        const bool wrp = (lane & 9) == 0;

#define CONV2_EPI(accv, instv)                                                 \
        {   float* p2o = s_p2 + (instv) * 256 + px;                            \
            _Pragma("unroll")                                                  \
            for (int ntl = 0; ntl < 4; ++ntl) {                                \
                _Pragma("unroll")                                              \
                for (int r = 0; r < 4; ++r) {                                  \
                    float v = accv[ntl][r];                                    \
                    v = fmaxf(v, __shfl_xor(v, 1));                            \
                    v = fmaxf(v, __shfl_xor(v, 8));                            \
                    v = fmaxf(v + bias4[r], 0.f);                              \
                    if (wrp) p2o[(g * 4 + r) * 16 + ntl * 4] = v;              \
                }                                                              \
            }                                                                  \
        }
        CONV2_EPI(accA, wv0);
        CONV2_EPI(accB, wv0 + 4);
#undef CONV2_EPI
    }
    __syncthreads();

    // ---- fc1: 256 -> 120, relu. 240 lanes; lane pair shares weight row,
    //      each lane does 4 instance-dots (fw1 read once per pair) ----
    if (tid < 240) {
        int o  = tid >> 1;                       // 0..119
        int pr = tid & 1;                        // instance group: 4*pr..4*pr+3
        const float4* wr = (const float4*)(fw1 + o * 256);
        const float4* q0 = (const float4*)(s_p2 + (4 * pr    ) * 256);
        const float4* q1 = (const float4*)(s_p2 + (4 * pr + 1) * 256);
        const float4* q2 = (const float4*)(s_p2 + (4 * pr + 2) * 256);
        const float4* q3 = (const float4*)(s_p2 + (4 * pr + 3) * 256);
        float a0 = 0.f, a1 = 0.f, a2 = 0.f, a3 = 0.f;
#pragma unroll 4
        for (int k = 0; k < 64; ++k) {
            float4 w4 = wr[k];
            float4 p;
            p = q0[k]; a0 = fmaf(w4.x,p.x,a0); a0 = fmaf(w4.y,p.y,a0); a0 = fmaf(w4.z,p.z,a0); a0 = fmaf(w4.w,p.w,a0);
            p = q1[k]; a1 = fmaf(w4.x,p.x,a1); a1 = fmaf(w4.y,p.y,a1); a1 = fmaf(w4.z,p.z,a1); a1 = fmaf(w4.w,p.w,a1);
            p = q2[k]; a2 = fmaf(w4.x,p.x,a2); a2 = fmaf(w4.y,p.y,a2); a2 = fmaf(w4.z,p.z,a2); a2 = fmaf(w4.w,p.w,a2);
            p = q3[k]; a3 = fmaf(w4.x,p.x,a3); a3 = fmaf(w4.y,p.y,a3); a3 = fmaf(w4.z,p.z,a3); a3 = fmaf(w4.w,p.w,a3);
        }
        float bb = fb1[o];
        s_f1[(4 * pr    ) * 120 + o] = fmaxf(a0 + bb, 0.f);
        s_f1[(4 * pr + 1) * 120 + o] = fmaxf(a1 + bb, 0.f);
        s_f1[(4 * pr + 2) * 120 + o] = fmaxf(a2 + bb, 0.f);
        s_f1[(4 * pr + 3) * 120 + o] = fmaxf(a3 + bb, 0.f);
    }
    __syncthreads();

    // ---- fc2: 120 -> 84, relu. 168 lanes, same pairing ----
    if (tid < 168) {
        int o  = tid >> 1;                       // 0..83
        int pr = tid & 1;
        const float4* wr = (const float4*)(fw2 + o * 120);
        const float4* q0 = (const float4*)(s_f1 + (4 * pr    ) * 120);
        const float4* q1 = (const float4*)(s_f1 + (4 * pr + 1) * 120);
        const float4* q2 = (const float4*)(s_f1 + (4 * pr + 2) * 120);
        const float4* q3 = (const float4*)(s_f1 + (4 * pr + 3) * 120);
        float a0 = 0.f, a1 = 0.f, a2 = 0.f, a3 = 0.f;
#pragma unroll 5
        for (int k = 0; k < 30; ++k) {
            float4 w4 = wr[k];
            float4 p;
            p = q0[k]; a0 = fmaf(w4.x,p.x,a0); a0 = fmaf(w4.y,p.y,a0); a0 = fmaf(w4.z,p.z,a0); a0 = fmaf(w4.w,p.w,a0);
            p = q1[k]; a1 = fmaf(w4.x,p.x,a1); a1 = fmaf(w4.y,p.y,a1); a1 = fmaf(w4.z,p.z,a1); a1 = fmaf(w4.w,p.w,a1);
            p = q2[k]; a2 = fmaf(w4.x,p.x,a2); a2 = fmaf(w4.y,p.y,a2); a2 = fmaf(w4.z,p.z,a2); a2 = fmaf(w4.w,p.w,a2);
            p = q3[k]; a3 = fmaf(w4.x,p.x,a3); a3 = fmaf(w4.y,p.y,a3); a3 = fmaf(w4.z,p.z,a3); a3 = fmaf(w4.w,p.w,a3);
        }
        float bb = fb2[o];
        s_f2[(4 * pr    ) * 84 + o] = fmaxf(a0 + bb, 0.f);
        s_f2[(4 * pr + 1) * 84 + o] = fmaxf(a1 + bb, 0.f);
        s_f2[(4 * pr + 2) * 84 + o] = fmaxf(a2 + bb, 0.f);
        s_f2[(4 * pr + 3) * 84 + o] = fmaxf(a3 + bb, 0.f);
    }
    __syncthreads();

    // ---- fc3: 84 -> 10. 80 lanes ----
    if (tid < 80) {
        int o    = tid % 10;
        int inst = tid / 10;                     // 0..7
        const float4* wr = (const float4*)(fw3 + o * 84);
        const float4* q0 = (const float4*)(s_f2 + inst * 84);
        float a0 = 0.f;
#pragma unroll
        for (int k = 0; k < 21; ++k) {
            float4 w4 = wr[k];
            float4 p = q0[k];
            a0 = fmaf(w4.x,p.x,a0); a0 = fmaf(w4.y,p.y,a0); a0 = fmaf(w4.z,p.z,a0); a0 = fmaf(w4.w,p.w,a0);
        }
        s_log[inst * 10 + o] = a0 + fb3[o];
    }
    __syncthreads();

    // ---- softmax (in-lane) + full convolution (len 19) + log ----
    if (tid < 19 * SPB) {
        int ls = tid / 19;                       // sample 0..3
        int t  = tid % 19;
        const float* la = &s_log[(ls * 2 + 0) * 10];
        const float* lb = &s_log[(ls * 2 + 1) * 10];
        float pa[10], pb[10];
        float mxa = la[0], mxb = lb[0];
#pragma unroll
        for (int j = 1; j < 10; ++j) { mxa = fmaxf(mxa, la[j]); mxb = fmaxf(mxb, lb[j]); }
        float sa = 0.f, sb = 0.f;
#pragma unroll
        for (int j = 0; j < 10; ++j) {
            pa[j] = __expf(la[j] - mxa); sa += pa[j];
            pb[j] = __expf(lb[j] - mxb); sb += pb[j];
        }
        float inv = 1.f / (sa * sb);
        int jlo = t - 9 > 0 ? t - 9 : 0;
        int jhi = t < 9 ? t : 9;
        float z = 0.f;
        for (int j = jlo; j <= jhi; ++j)
            z += pa[j] * pb[t - j];
        out[(size_t)(b0 + ls) * 19 + t] = __logf(z * inv);
    }
}

extern "C" void kernel_launch(void* const* d_in, const int* in_sizes, int n_in,
                              void* d_out, int out_size, void* d_ws, size_t ws_size,
                              hipStream_t stream) {
    const float* x   = (const float*)d_in[0];
    const float* cw1 = (const float*)d_in[1];
    const float* cb1 = (const float*)d_in[2];
    const float* cw2 = (const float*)d_in[3];
    const float* cb2 = (const float*)d_in[4];
    const float* fw1 = (const float*)d_in[5];
    const float* fb1 = (const float*)d_in[6];
    const float* fw2 = (const float*)d_in[7];
    const float* fb2 = (const float*)d_in[8];
    const float* fw3 = (const float*)d_in[9];
    const float* fb3 = (const float*)d_in[10];
    float* out = (float*)d_out;

    const int B = in_sizes[0] / (2 * 28 * 28);   // 16384

    lenet_fused<<<B / SPB, 256, 0, stream>>>(x, cw1, cb1, cw2, cb2,
                                             fw1, fb1, fw2, fb2, fw3, fb3, out);
}

// Round 4
// 329.968 us; speedup vs baseline: 1.1305x; 1.1305x over previous
//
#include <hip/hip_runtime.h>
#include <math.h>

// Fused dual-LeNet + len-19 full convolution + log.
// Round-14: conv1-MFMA restructured for ILP (R13 regressed: 5-deep dependent
// MFMA chains per tile -> latency-bound, VALUBusy 39%, MfmaUtil 6%).
//  * loop nest swapped: ks outer, xbi inner, 6 INDEPENDENT accumulators ->
//    every group of 6 MFMAs is independent, pipe issues back-to-back.
//  * epilogue (48 independent chains) runs after the MFMA block.
//  * image staging vectorized: float4 in -> 4 (hi,lo) f16 pairs -> one 16B
//    LDS write (R13 used scalar loads).
//  * math identical to R13 (passed, absmax 0.03125): shift-packed B
//    (4 shifts x 6 ch), hi/lo-split exact image, K=80, M=32 rows.
// conv2 (MFMA, R11), fc1/fc2/fc3/tail (R12) unchanged. LDS 45.4 KB, 3 blk/CU.

#define SPB 4            // samples per block (2 pairs, 8 instances)
#define P1H_IN 440       // s_p1h instance stride in half2
#define P1H_IC 144       // channel-pair stride in half2 (3 pairs per inst)

typedef _Float16 f16x2 __attribute__((ext_vector_type(2)));
typedef _Float16 half8 __attribute__((ext_vector_type(8)));
typedef float floatx4 __attribute__((ext_vector_type(4)));
typedef float floatx16 __attribute__((ext_vector_type(16)));

__global__ __launch_bounds__(256, 3) void lenet_fused(
    const float* __restrict__ x,     // [B,2,28,28]
    const float* __restrict__ cw1,   // [6,1,5,5]
    const float* __restrict__ cb1,   // [6]
    const float* __restrict__ cw2,   // [16,6,5,5]
    const float* __restrict__ cb2,   // [16]
    const float* __restrict__ fw1,   // [120,256]
    const float* __restrict__ fb1,   // [120]
    const float* __restrict__ fw2,   // [84,120]
    const float* __restrict__ fb2,   // [84]
    const float* __restrict__ fw3,   // [10,84]
    const float* __restrict__ fb3,   // [10]
    float* __restrict__ out)         // [B,19]
{
    const int tid = threadIdx.x;
    const int b0  = blockIdx.x * SPB;

    __shared__ __align__(16) float s_pool[8 * 784];      // 25088 B (imgHL; reused)
    __shared__ __align__(16) f16x2 s_p1h [8 * P1H_IN];   // 14080 B
    __shared__ __align__(16) float s_w1t [25 * 8];       //   800 B  [k][o]
    __shared__ float s_b1[8];
    __shared__ __align__(16) f16x2 s_w2A [16 * 84];      //  5376 B  [o][kp]
    __shared__ float s_b2[16];
    // total ~45.4 KB -> 3 blocks/CU

    f16x2* s_imgHL = (f16x2*)s_pool;  // [8 inst][28][28] (hi,lo) pairs
    float* s_p2  = s_pool;           // 2048
    float* s_f1  = s_pool + 2048;    // 960
    float* s_f2  = s_pool + 3008;    // 672
    float* s_log = s_pool + 3680;    // 80

    // ---- stage images (hi/lo split, vectorized) + weights ----
    {
        const float4* xb = (const float4*)(x + (size_t)b0 * 1568);
        float4* sh = (float4*)s_imgHL;
        for (int i = tid; i < 1568; i += 256) {
            float4 q = xb[i];
            union { f16x2 h[4]; float4 v; } u;
            u.h[0].x = (_Float16)q.x; u.h[0].y = (_Float16)(q.x - (float)u.h[0].x);
            u.h[1].x = (_Float16)q.y; u.h[1].y = (_Float16)(q.y - (float)u.h[1].x);
            u.h[2].x = (_Float16)q.z; u.h[2].y = (_Float16)(q.z - (float)u.h[2].x);
            u.h[3].x = (_Float16)q.w; u.h[3].y = (_Float16)(q.w - (float)u.h[3].x);
            sh[i] = u.v;
        }
    }
    for (int i = tid; i < 150; i += 256) {       // cw1 -> [k][o], stride 8
        int o = i / 25, k = i % 25;
        s_w1t[k * 8 + o] = cw1[i];
    }
    for (int i = tid; i < 16 * 84; i += 256) {   // cw2 -> MFMA A rows [o][kp]
        int o = i / 84, kp = i % 84;
        f16x2 w2;
        if (kp < 75) {
            int icp = kp / 25, r = kp % 25;      // kp = icp*25 + ky*5 + kx
            float we = cw2[o * 150 + (2 * icp    ) * 25 + r];
            float wo = cw2[o * 150 + (2 * icp + 1) * 25 + r];
            w2.x = (_Float16)we; w2.y = (_Float16)wo;
        } else {
            w2.x = (_Float16)0.f; w2.y = (_Float16)0.f;
        }
        s_w2A[i] = w2;
    }
    if (tid < 8)  s_b1[tid] = (tid < 6) ? cb1[tid] : 0.f;
    if (tid < 16) s_b2[tid] = cb2[tid];
    __syncthreads();

    // ---- conv1 5x5 (1->6) + pool2x2 + relu : MFMA 32x32x16 f16 ----
    // D[32 rows = Y0 (24 valid)][32 cols = (s,ch), 24 valid]; ks outer,
    // xbi inner with 6 independent accs; A-frag = one aligned b128.
    {
        const int lane = tid & 63;
        const int wv   = tid >> 6;
        const int l5   = lane >> 5;
        const int cn   = lane & 31;
        const int s    = cn >> 3;                // x-shift 0..3
        const int ch   = cn & 7;                 // channel 0..7 (<6 valid)
        const int Y0   = cn < 24 ? cn : 23;      // A-row pixel row (clamped)

        // B fragments: B[k' = ks*16 + l5*8 + j][(s,ch)] = w1[ch][ks][kx'-s],
        // kx' = l5*4 + (j>>1), both h-slots identical.
        half8 bfr[5];
#pragma unroll
        for (int ks = 0; ks < 5; ++ks) {
            float w4[4];
#pragma unroll
            for (int q = 0; q < 4; ++q) {
                int kx = l5 * 4 + q - s;
                float wq = 0.f;
                if (ch < 6 && kx >= 0 && kx <= 4)
                    wq = s_w1t[(ks * 5 + kx) * 8 + ch];
                w4[q] = wq;
            }
            half8 b;
            b[0] = (_Float16)w4[0]; b[1] = b[0];
            b[2] = (_Float16)w4[1]; b[3] = b[2];
            b[4] = (_Float16)w4[2]; b[5] = b[4];
            b[6] = (_Float16)w4[3]; b[7] = b[6];
            bfr[ks] = b;
        }
        const float bch = s_b1[ch];
        const int   ybase = Y0 * 28 + l5 * 4;    // half2 units (mod 4 == 0)
        const bool  wrl   = ((s & 1) == 0) && (ch < 6);
        _Float16* p1w = (_Float16*)s_p1h;

        floatx16 zero16 = {0.f,0.f,0.f,0.f, 0.f,0.f,0.f,0.f,
                           0.f,0.f,0.f,0.f, 0.f,0.f,0.f,0.f};

#pragma unroll 1
        for (int ih = 0; ih < 2; ++ih) {
            const int inst = wv + 4 * ih;
            const f16x2* ip = s_imgHL + inst * 784 + ybase;
            const int wb = (inst * P1H_IN + (ch >> 1) * P1H_IC) * 2 + (ch & 1);

            floatx16 acc[6];
#pragma unroll
            for (int xbi = 0; xbi < 6; ++xbi) acc[xbi] = zero16;

#pragma unroll
            for (int ks = 0; ks < 5; ++ks) {
                const f16x2* rp = ip + ks * 28;
#pragma unroll
                for (int xbi = 0; xbi < 6; ++xbi) {
                    half8 a = *(const half8*)(rp + xbi * 4);
                    acc[xbi] = __builtin_amdgcn_mfma_f32_32x32x16_f16(
                        a, bfr[ks], acc[xbi], 0, 0, 0);
                }
            }

            // epilogue: 6 xbi x 8 outputs, all independent.
            // D row = (reg&3) + 8*(reg>>2) + 4*l5 = Y0; col = (s,ch).
#pragma unroll
            for (int xbi = 0; xbi < 6; ++xbi) {
                const int px2 = (xbi * 2 + (s >> 1)) * 2;   // px in halves
#pragma unroll
                for (int d = 0; d < 4; ++d) {
#pragma unroll
                    for (int cp = 0; cp < 2; ++cp) {
                        float vy = fmaxf(acc[xbi][4 * d + 2 * cp],
                                         acc[xbi][4 * d + 2 * cp + 1]); // y-pool
                        float vo = __shfl_xor(vy, 8);              // s^1 col
                        float vp = fmaxf(vy, vo);                  // x-pool
                        float r  = fmaxf(vp + bch, 0.f);
                        int  py  = cp + 4 * d + 2 * l5;
                        if (wrl && py < 12)
                            p1w[wb + py * 24 + px2] = (_Float16)r;
                    }
                }
            }
        }
    }
    __syncthreads();

    // ---- conv2 5x5 (6->16) + pool2x2 + relu : MFMA 16x16x32 f16 ----
    {
        const int lane = tid & 63;
        const int wv0  = tid >> 6;               // instance pair: wv0, wv0+4
        const int g    = lane >> 4;              // k-group
        const int cn   = lane & 15;              // A row (=o) / B col (=n%16)

        half8 afr[5];
        const _Float16* wA = (const _Float16*)s_w2A;
#pragma unroll
        for (int ks = 0; ks < 5; ++ks)
            afr[ks] = *(const half8*)(wA + cn * 168 + ks * 32 + g * 8);

        float bias4[4];
#pragma unroll
        for (int r = 0; r < 4; ++r) bias4[r] = s_b2[g * 4 + r];

        const int csb = (cn >> 3) * 12 + (cn & 7);           // + 24*ntl per tile
        const f16x2* pbA = s_p1h + wv0 * P1H_IN + csb;
        const f16x2* pbB = pbA + 4 * P1H_IN;

        floatx4 zero4 = {0.f, 0.f, 0.f, 0.f};
        floatx4 accA[4] = {zero4, zero4, zero4, zero4};
        floatx4 accB[4] = {zero4, zero4, zero4, zero4};

#pragma unroll
        for (int ks = 0; ks < 5; ++ks) {
            int ko[4];
#pragma unroll
            for (int j = 0; j < 4; ++j) {
                int kp = ks * 16 + g * 4 + j;
                kp = kp > 74 ? 74 : kp;          // clamp: garbage meets zero A
                int icp = (int)((unsigned)kp / 25u);
                int r   = kp - icp * 25;
                int ky  = (int)((unsigned)r / 5u);
                int kx  = r - ky * 5;
                ko[j] = icp * P1H_IC + ky * 12 + kx;
            }
#pragma unroll
            for (int ntl = 0; ntl < 4; ++ntl) {
                union { half8 h8; f16x2 h2[4]; } bpA, bpB;
                bpA.h2[0] = pbA[ko[0] + 24 * ntl];
                bpA.h2[1] = pbA[ko[1] + 24 * ntl];
                bpA.h2[2] = pbA[ko[2] + 24 * ntl];
                bpA.h2[3] = pbA[ko[3] + 24 * ntl];
                bpB.h2[0] = pbB[ko[0] + 24 * ntl];
                bpB.h2[1] = pbB[ko[1] + 24 * ntl];
                bpB.h2[2] = pbB[ko[2] + 24 * ntl];
                bpB.h2[3] = pbB[ko[3] + 24 * ntl];
                accA[ntl] = __builtin_amdgcn_mfma_f32_16x16x32_f16(
                    afr[ks], bpA.h8, accA[ntl], 0, 0, 0);
                accB[ntl] = __builtin_amdgcn_mfma_f32_16x16x32_f16(
                    afr[ks], bpB.h8, accB[ntl], 0, 0, 0);
            }
        }

        const int px = (lane & 7) >> 1;
        const bool wrp = (lane & 9) == 0;

#define CONV2_EPI(accv, instv)                                                 \
        {   float* p2o = s_p2 + (instv) * 256 + px;                            \
            _Pragma("unroll")                                                  \
            for (int ntl = 0; ntl < 4; ++ntl) {                                \
                _Pragma("unroll")                                              \
                for (int r = 0; r < 4; ++r) {                                  \
                    float v = accv[ntl][r];                                    \
                    v = fmaxf(v, __shfl_xor(v, 1));                            \
                    v = fmaxf(v, __shfl_xor(v, 8));                            \
                    v = fmaxf(v + bias4[r], 0.f);                              \
                    if (wrp) p2o[(g * 4 + r) * 16 + ntl * 4] = v;              \
                }                                                              \
            }                                                                  \
        }
        CONV2_EPI(accA, wv0);
        CONV2_EPI(accB, wv0 + 4);
#undef CONV2_EPI
    }
    __syncthreads();

    // ---- fc1: 256 -> 120, relu. 240 lanes; lane pair shares weight row,
    //      each lane does 4 instance-dots (fw1 read once per pair) ----
    if (tid < 240) {
        int o  = tid >> 1;                       // 0..119
        int pr = tid & 1;                        // instance group: 4*pr..4*pr+3
        const float4* wr = (const float4*)(fw1 + o * 256);
        const float4* q0 = (const float4*)(s_p2 + (4 * pr    ) * 256);
        const float4* q1 = (const float4*)(s_p2 + (4 * pr + 1) * 256);
        const float4* q2 = (const float4*)(s_p2 + (4 * pr + 2) * 256);
        const float4* q3 = (const float4*)(s_p2 + (4 * pr + 3) * 256);
        float a0 = 0.f, a1 = 0.f, a2 = 0.f, a3 = 0.f;
#pragma unroll 4
        for (int k = 0; k < 64; ++k) {
            float4 w4 = wr[k];
            float4 p;
            p = q0[k]; a0 = fmaf(w4.x,p.x,a0); a0 = fmaf(w4.y,p.y,a0); a0 = fmaf(w4.z,p.z,a0); a0 = fmaf(w4.w,p.w,a0);
            p = q1[k]; a1 = fmaf(w4.x,p.x,a1); a1 = fmaf(w4.y,p.y,a1); a1 = fmaf(w4.z,p.z,a1); a1 = fmaf(w4.w,p.w,a1);
            p = q2[k]; a2 = fmaf(w4.x,p.x,a2); a2 = fmaf(w4.y,p.y,a2); a2 = fmaf(w4.z,p.z,a2); a2 = fmaf(w4.w,p.w,a2);
            p = q3[k]; a3 = fmaf(w4.x,p.x,a3); a3 = fmaf(w4.y,p.y,a3); a3 = fmaf(w4.z,p.z,a3); a3 = fmaf(w4.w,p.w,a3);
        }
        float bb = fb1[o];
        s_f1[(4 * pr    ) * 120 + o] = fmaxf(a0 + bb, 0.f);
        s_f1[(4 * pr + 1) * 120 + o] = fmaxf(a1 + bb, 0.f);
        s_f1[(4 * pr + 2) * 120 + o] = fmaxf(a2 + bb, 0.f);
        s_f1[(4 * pr + 3) * 120 + o] = fmaxf(a3 + bb, 0.f);
    }
    __syncthreads();

    // ---- fc2: 120 -> 84, relu. 168 lanes, same pairing ----
    if (tid < 168) {
        int o  = tid >> 1;                       // 0..83
        int pr = tid & 1;
        const float4* wr = (const float4*)(fw2 + o * 120);
        const float4* q0 = (const float4*)(s_f1 + (4 * pr    ) * 120);
        const float4* q1 = (const float4*)(s_f1 + (4 * pr + 1) * 120);
        const float4* q2 = (const float4*)(s_f1 + (4 * pr + 2) * 120);
        const float4* q3 = (const float4*)(s_f1 + (4 * pr + 3) * 120);
        float a0 = 0.f, a1 = 0.f, a2 = 0.f, a3 = 0.f;
#pragma unroll 5
        for (int k = 0; k < 30; ++k) {
            float4 w4 = wr[k];
            float4 p;
            p = q0[k]; a0 = fmaf(w4.x,p.x,a0); a0 = fmaf(w4.y,p.y,a0); a0 = fmaf(w4.z,p.z,a0); a0 = fmaf(w4.w,p.w,a0);
            p = q1[k]; a1 = fmaf(w4.x,p.x,a1); a1 = fmaf(w4.y,p.y,a1); a1 = fmaf(w4.z,p.z,a1); a1 = fmaf(w4.w,p.w,a1);
            p = q2[k]; a2 = fmaf(w4.x,p.x,a2); a2 = fmaf(w4.y,p.y,a2); a2 = fmaf(w4.z,p.z,a2); a2 = fmaf(w4.w,p.w,a2);
            p = q3[k]; a3 = fmaf(w4.x,p.x,a3); a3 = fmaf(w4.y,p.y,a3); a3 = fmaf(w4.z,p.z,a3); a3 = fmaf(w4.w,p.w,a3);
        }
        float bb = fb2[o];
        s_f2[(4 * pr    ) * 84 + o] = fmaxf(a0 + bb, 0.f);
        s_f2[(4 * pr + 1) * 84 + o] = fmaxf(a1 + bb, 0.f);
        s_f2[(4 * pr + 2) * 84 + o] = fmaxf(a2 + bb, 0.f);
        s_f2[(4 * pr + 3) * 84 + o] = fmaxf(a3 + bb, 0.f);
    }
    __syncthreads();

    // ---- fc3: 84 -> 10. 80 lanes ----
    if (tid < 80) {
        int o    = tid % 10;
        int inst = tid / 10;                     // 0..7
        const float4* wr = (const float4*)(fw3 + o * 84);
        const float4* q0 = (const float4*)(s_f2 + inst * 84);
        float a0 = 0.f;
#pragma unroll
        for (int k = 0; k < 21; ++k) {
            float4 w4 = wr[k];
            float4 p = q0[k];
            a0 = fmaf(w4.x,p.x,a0); a0 = fmaf(w4.y,p.y,a0); a0 = fmaf(w4.z,p.z,a0); a0 = fmaf(w4.w,p.w,a0);
        }
        s_log[inst * 10 + o] = a0 + fb3[o];
    }
    __syncthreads();

    // ---- softmax (in-lane) + full convolution (len 19) + log ----
    if (tid < 19 * SPB) {
        int ls = tid / 19;                       // sample 0..3
        int t  = tid % 19;
        const float* la = &s_log[(ls * 2 + 0) * 10];
        const float* lb = &s_log[(ls * 2 + 1) * 10];
        float pa[10], pb[10];
        float mxa = la[0], mxb = lb[0];
#pragma unroll
        for (int j = 1; j < 10; ++j) { mxa = fmaxf(mxa, la[j]); mxb = fmaxf(mxb, lb[j]); }
        float sa = 0.f, sb = 0.f;
#pragma unroll
        for (int j = 0; j < 10; ++j) {
            pa[j] = __expf(la[j] - mxa); sa += pa[j];
            pb[j] = __expf(lb[j] - mxb); sb += pb[j];
        }
        float inv = 1.f / (sa * sb);
        int jlo = t - 9 > 0 ? t - 9 : 0;
        int jhi = t < 9 ? t : 9;
        float z = 0.f;
        for (int j = jlo; j <= jhi; ++j)
            z += pa[j] * pb[t - j];
        out[(size_t)(b0 + ls) * 19 + t] = __logf(z * inv);
    }
}

extern "C" void kernel_launch(void* const* d_in, const int* in_sizes, int n_in,
                              void* d_out, int out_size, void* d_ws, size_t ws_size,
                              hipStream_t stream) {
    const float* x   = (const float*)d_in[0];
    const float* cw1 = (const float*)d_in[1];
    const float* cb1 = (const float*)d_in[2];
    const float* cw2 = (const float*)d_in[3];
    const float* cb2 = (const float*)d_in[4];
    const float* fw1 = (const float*)d_in[5];
    const float* fb1 = (const float*)d_in[6];
    const float* fw2 = (const float*)d_in[7];
    const float* fb2 = (const float*)d_in[8];
    const float* fw3 = (const float*)d_in[9];
    const float* fb3 = (const float*)d_in[10];
    float* out = (float*)d_out;

    const int B = in_sizes[0] / (2 * 28 * 28);   // 16384

    lenet_fused<<<B / SPB, 256, 0, stream>>>(x, cw1, cb1, cw2, cb2,
                                             fw1, fb1, fw2, fb2, fw3, fb3, out);
}